// Round 1
// baseline (79.289 us; speedup 1.0000x reference)
//
#include <hip/hip_runtime.h>

// MetaUpSample: out[b,ho,wo,f] = sum_k patch[b,ho,wo,k] * meta_w[b,ho,wo,k*3+f]
// B=4, H=W=64, C=64, Ho=Wo=128, ksize=3x3, FILTERS=3, K=576.
// One wave (64 lanes) per output pixel; lane index == channel index.
// Memory-bound on the single streaming read of meta_w (453 MB).

struct F3 { float x, y, z; };  // 12-byte, 4-aligned weight triple (f=0,1,2 for one k)

__global__ __launch_bounds__(256) void meta_upsample_kernel(
    const float* __restrict__ x,     // [4,64,64,64]
    const float* __restrict__ mw,    // [4,128,128,1728]
    float* __restrict__ out)         // [4,128,128,3]
{
    const int lane = threadIdx.x & 63;
    const int wave = threadIdx.x >> 6;
    const int pix  = blockIdx.x * 4 + wave;        // ((b*128 + ho)*128 + wo), < 65536

    const int wo = pix & 127;
    const int ho = (pix >> 7) & 127;
    const int b  = pix >> 14;
    const int hs = (ho >> 1) - 1;                  // top row of 3x3 patch (pad=1)
    const int ws = (wo >> 1) - 1;                  // left col of 3x3 patch

    const float* __restrict__ xb = x + (size_t)b * (64 * 64 * 64);
    const float* __restrict__ wp = mw + (size_t)pix * 1728;

    float a0 = 0.f, a1 = 0.f, a2 = 0.f;

#pragma unroll
    for (int t = 0; t < 9; ++t) {                  // tap = dh*3+dw
        const int dh = t / 3, dw = t % 3;
        const int hh = hs + dh;
        const int ww = ws + dw;
        float p = 0.f;
        if ((unsigned)hh < 64u && (unsigned)ww < 64u)
            p = xb[(((hh << 6) + ww) << 6) + lane];          // coalesced 256B, L1/L2-hot
        const F3 w = *reinterpret_cast<const F3*>(wp + t * 192 + lane * 3);  // 768B/wave contiguous
        a0 += w.x * p;
        a1 += w.y * p;
        a2 += w.z * p;
    }

    // 64-lane butterfly all-reduce of the three filter accumulators
#pragma unroll
    for (int off = 32; off >= 1; off >>= 1) {
        a0 += __shfl_xor(a0, off, 64);
        a1 += __shfl_xor(a1, off, 64);
        a2 += __shfl_xor(a2, off, 64);
    }

    if (lane == 0) {
        float* o = out + (size_t)pix * 3;
        o[0] = a0; o[1] = a1; o[2] = a2;
    }
}

extern "C" void kernel_launch(void* const* d_in, const int* in_sizes, int n_in,
                              void* d_out, int out_size, void* d_ws, size_t ws_size,
                              hipStream_t stream) {
    const float* x  = (const float*)d_in[0];   // 4*64*64*64   = 1,048,576 floats
    const float* mw = (const float*)d_in[1];   // 4*128*128*1728 = 113,246,208 floats
    float* out = (float*)d_out;                // 4*128*128*3  = 196,608 floats

    const int n_pix   = 4 * 128 * 128;         // 65536 pixels, one wave each
    const int blocks  = n_pix / 4;             // 4 waves per 256-thread block
    meta_upsample_kernel<<<blocks, 256, 0, stream>>>(x, mw, out);
}

// Round 2
// 71.206 us; speedup vs baseline: 1.1135x; 1.1135x over previous
//
#include <hip/hip_runtime.h>

// MetaUpSample: out[b,ho,wo,f] = sum_k patch[b,ho,wo,k] * meta_w[b,ho,wo,k*3+f]
// B=4, H=W=64, C=64, Ho=Wo=128, 3x3 taps, FILTERS=3, K=576.
//
// v2: one wave per 2x2 output quad. All 4 pixels of a quad share the SAME
// source patch (h_src=ho>>1, w_src=wo>>1), so patches load once per quad
// (4x fewer x-side loads). meta_w (453 MB, zero reuse) is read with
// non-temporal loads so it doesn't evict the 4 MB x from L2/L3.
// Lane == channel; per-tap weight triples are contiguous 768 B per wave.

__global__ __launch_bounds__(256) void meta_upsample_quad(
    const float* __restrict__ x,     // [4,64,64,64]
    const float* __restrict__ mw,    // [4,128,128,1728]
    float* __restrict__ out)         // [4,128,128,3]
{
    const int lane = threadIdx.x & 63;
    const int wave = threadIdx.x >> 6;
    const int q    = blockIdx.x * 4 + wave;     // quad id, < 16384

    const int j = q & 63;                       // wo = 2j, 2j+1
    const int i = (q >> 6) & 63;                // ho = 2i, 2i+1
    const int b = q >> 12;

    const int hs = i - 1;                       // top row of shared 3x3 patch
    const int ws = j - 1;                       // left col

    const float* __restrict__ xb = x + (size_t)b * (64 * 64 * 64);
    const size_t pixrow0 = (size_t)(b * 128 + 2 * i) * 128 + 2 * j;
    const float* __restrict__ wp00 = mw + pixrow0 * 1728;          // (2i,   2j)
    const float* __restrict__ wp01 = wp00 + 1728;                  // (2i,   2j+1)
    const float* __restrict__ wp10 = wp00 + (size_t)128 * 1728;    // (2i+1, 2j)
    const float* __restrict__ wp11 = wp10 + 1728;                  // (2i+1, 2j+1)

    float a[12] = {};  // [pixel(00,01,10,11) * 3 + f], all indices compile-time

#pragma unroll
    for (int t = 0; t < 9; ++t) {               // tap = dh*3+dw
        const int dh = t / 3, dw = t % 3;
        const int hh = hs + dh;
        const int ww = ws + dw;
        float p = 0.f;
        if ((unsigned)hh < 64u && (unsigned)ww < 64u)
            p = xb[(((hh << 6) + ww) << 6) + lane];   // shared by all 4 pixels

        const int wo_off = t * 192 + lane * 3;
        const float* b00 = wp00 + wo_off;
        const float* b01 = wp01 + wo_off;
        const float* b10 = wp10 + wo_off;
        const float* b11 = wp11 + wo_off;

        // non-temporal streaming reads (453 MB, zero reuse)
        float w;
        w = __builtin_nontemporal_load(b00 + 0); a[0]  += w * p;
        w = __builtin_nontemporal_load(b00 + 1); a[1]  += w * p;
        w = __builtin_nontemporal_load(b00 + 2); a[2]  += w * p;
        w = __builtin_nontemporal_load(b01 + 0); a[3]  += w * p;
        w = __builtin_nontemporal_load(b01 + 1); a[4]  += w * p;
        w = __builtin_nontemporal_load(b01 + 2); a[5]  += w * p;
        w = __builtin_nontemporal_load(b10 + 0); a[6]  += w * p;
        w = __builtin_nontemporal_load(b10 + 1); a[7]  += w * p;
        w = __builtin_nontemporal_load(b10 + 2); a[8]  += w * p;
        w = __builtin_nontemporal_load(b11 + 0); a[9]  += w * p;
        w = __builtin_nontemporal_load(b11 + 1); a[10] += w * p;
        w = __builtin_nontemporal_load(b11 + 2); a[11] += w * p;
    }

    // 64-lane butterfly all-reduce of all 12 accumulators
#pragma unroll
    for (int off = 32; off >= 1; off >>= 1) {
#pragma unroll
        for (int v = 0; v < 12; ++v)
            a[v] += __shfl_xor(a[v], off, 64);
    }

    // Store: row ho=2i gets pixels (00,01), row ho=2i+1 gets (10,11).
    // Byte offsets are multiples of 24 -> float2 stores are 8B-aligned.
    if (lane == 0) {
        float* o = out + pixrow0 * 3;
        *reinterpret_cast<float2*>(o + 0) = make_float2(a[0], a[1]);
        *reinterpret_cast<float2*>(o + 2) = make_float2(a[2], a[3]);
        *reinterpret_cast<float2*>(o + 4) = make_float2(a[4], a[5]);
    } else if (lane == 1) {
        float* o = out + (pixrow0 + 128) * 3;
        *reinterpret_cast<float2*>(o + 0) = make_float2(a[6], a[7]);
        *reinterpret_cast<float2*>(o + 2) = make_float2(a[8], a[9]);
        *reinterpret_cast<float2*>(o + 4) = make_float2(a[10], a[11]);
    }
}

extern "C" void kernel_launch(void* const* d_in, const int* in_sizes, int n_in,
                              void* d_out, int out_size, void* d_ws, size_t ws_size,
                              hipStream_t stream) {
    const float* x  = (const float*)d_in[0];
    const float* mw = (const float*)d_in[1];
    float* out = (float*)d_out;

    const int n_quads = 4 * 64 * 64;            // 16384 quads, one wave each
    const int blocks  = n_quads / 4;            // 4 waves per 256-thread block
    meta_upsample_quad<<<blocks, 256, 0, stream>>>(x, mw, out);
}